// Round 4
// baseline (467.751 us; speedup 1.0000x reference)
//
#include <hip/hip_runtime.h>

// PINNLayer — NN=100000, NE=3200000. fp32 in, fp32 out.
// d_out fp32: [ result (NN) | out2 (NE,3) rows = [src,dst,val] ].
//
// Round-9: rounds 7/8 proved edge_scatter's 104us is NOT the record stores —
// it's L1-port amplification from 48B-lane-stride float4 flow reads (9 loads
// re-walking the same lines: ~9x48 lines/wave through the L1 port ≈ 35us) plus
// stride-12B scalar out2 stores. Fix: separable conv
//    val[e] = b + P0[e] + P1[e+1] + P2[e+2],  P_kh[row] = dot(flow_row, w_kh)
// Each flow float4 is loaded ONCE, lane-coalesced; 3 dot4s -> LDS row tables;
// out2 staged in LDS, flushed as coalesced float4. Bucket scatter kept
// (feeds the single-pass accum_b); dsti array replaced by recompute -> LDS
// union ~17KB -> 8 blocks/CU ceiling.
//   P1 edge_scatter: coalesced conv + out2 + LDS-sorted bucket scatter.
//   P2 accum_b: 7 windows x 32 slices; every record read exactly once.
//   P3 node_final_b: reduce 32 partials + compose.
// Fallback to the proven round-5 pipeline if ws_size too small.

#define WSH    14
#define WSZ    16384    // nodes per window (128KB LDS for two fp32 tables)
#define SLC    32       // slices per window -> grid 7*32 = 224 blocks
#define EPT    4        // 256-edge tiles per block in edge_scatter
#define MAXWIN 16       // max windows supported
#define OVSLOT 32       // tail slot index for the overflow arena

// old-path constants (fallback)
#define OWSH 13
#define OWSZ 8192
#define OPB  16
#define OFPS 8192.0f
#define OQBIAS (1 << 20)
#define OQCLMP ((1 << 19) - 1)

// ---------------------------------------------------------------------------
// prep: conc gather; zero bucket tails (full path) or acc (fallback path).
__global__ __launch_bounds__(256) void prep(
    const float* __restrict__ od,
    float* __restrict__ conc,
    unsigned long long* __restrict__ acc,
    unsigned* __restrict__ tails,      // padded: tail[i] at tails[i<<4]
    int n_nodes)
{
    if (blockIdx.x == 0 && tails && threadIdx.x <= OVSLOT)
        tails[(size_t)threadIdx.x << 4] = 0u;
    int n = blockIdx.x * blockDim.x + threadIdx.x;
    if (n >= n_nodes) return;
    conc[n] = od[(long long)n * 48 + 45];   // origin_data[n,15,0]
    if (acc) acc[n] = 0ULL;
}

// ---------------------------------------------------------------------------
// P1 (full): separable coalesced conv + out2 + LDS-staged bucket scatter.
// w[t] (t<36): t = kh*12 + kw*4 + i  ->  conv_w[i*9+kh*3+kw];  w[36] = bias.
// A-record {s, val} -> bucket s>>WSH;  B-record {d, val*conc[s]} -> bucket n_win+(d>>WSH)
__global__ __launch_bounds__(256) void edge_scatter(
    const float* __restrict__ flow, const int* __restrict__ ei,
    const float* __restrict__ conv_w, const float* __restrict__ conv_b,
    const float* __restrict__ conc,
    float* __restrict__ out2,
    uint2* __restrict__ rec,           // NB buckets x cap records
    uint2* __restrict__ ovf,
    unsigned* __restrict__ tails,
    int n_edges, int n_win, unsigned cap, unsigned ocap)
{
    __shared__ float    w[40];
    __shared__ unsigned cnt[2 * MAXWIN];
    __shared__ unsigned sst[2 * MAXWIN + 1];   // exclusive scan + total sentinel
    __shared__ unsigned bas[2 * MAXWIN];       // global reservation base
    __shared__ unsigned stot;
    // phase A: R[3][258] rows + O[768] out2 tile (6192B)
    // phase B: stg[2048] records (16384B)      -- disjoint in time
    __shared__ __align__(16) char smem[16384];
    float* R   = (float*)smem;                 // R[r*258 + row], 774 floats
    float* O   = (float*)smem + 780;           // 768 floats, 16B-aligned (780*4=3120)
    uint2* stg = (uint2*)smem;

    const int t  = threadIdx.x;
    const int NB = 2 * n_win;
    if (t < 36) {
        int i  = t & 3;
        int kw = (t >> 2) % 3;
        int kh = t / 12;
        w[t] = conv_w[i * 9 + kh * 3 + kw];
    }
    if (t == 36) w[36] = conv_b[0];
    if (t < 2 * MAXWIN) cnt[t] = 0u;
    // pre-zero R for first round
    for (int i = t; i < 774; i += 256) R[i] = 0.f;
    __syncthreads();

    uint2    payA[EPT], payB[EPT];
    unsigned posA[EPT], posB[EPT];
#pragma unroll
    for (int k = 0; k < EPT; ++k) { posA[k] = 0xffffffffu; posB[k] = 0xffffffffu; }

    // ---- per-tile: coalesced conv + compose + out2 + histogram ----
#pragma unroll
    for (int k = 0; k < EPT; ++k) {
        const long long E0 = (long long)blockIdx.x * (256 * EPT) + (long long)k * 256;
        if (E0 >= n_edges) break;
        const int nrows = (int)(((long long)n_edges + 2 - E0) < 258 ?
                                ((long long)n_edges + 2 - E0) : 258);
        const int nf4 = 3 * nrows;

        // coalesced flow read: thread i loads float4 #i of the tile (ONE touch)
        const float4* fb = (const float4*)flow + E0 * 3;
        for (int i = t; i < nf4; i += 256) {
            float4 v = fb[i];
            int row = i / 3;
            int kk  = (i - row * 3) << 2;            // 0,4,8
            float d0 = fmaf(v.x, w[kk +  0], fmaf(v.y, w[kk +  1],
                       fmaf(v.z, w[kk +  2], v.w * w[kk +  3])));
            float d1 = fmaf(v.x, w[kk + 12], fmaf(v.y, w[kk + 13],
                       fmaf(v.z, w[kk + 14], v.w * w[kk + 15])));
            float d2 = fmaf(v.x, w[kk + 24], fmaf(v.y, w[kk + 25],
                       fmaf(v.z, w[kk + 26], v.w * w[kk + 27])));
            atomicAdd(&R[row],       d0);
            atomicAdd(&R[258 + row], d1);
            atomicAdd(&R[516 + row], d2);
        }
        __syncthreads();

        const long long e = E0 + t;
        if (e < n_edges) {
            float val = w[36] + R[t] + R[258 + t + 1] + R[516 + t + 2];
            int s = ei[e];
            int d = ei[n_edges + e];
            float cs = conc[s];                      // L2-resident gather (400KB)
            O[t * 3 + 0] = (float)s;
            O[t * 3 + 1] = (float)d;
            O[t * 3 + 2] = val;
            if (s != d) {
                payA[k].x = (unsigned)s; payA[k].y = __float_as_uint(val);
                payB[k].x = (unsigned)d; payB[k].y = __float_as_uint(val * cs);
                posA[k] = atomicAdd(&cnt[(unsigned)s >> WSH], 1u);
                posB[k] = atomicAdd(&cnt[n_win + ((unsigned)d >> WSH)], 1u);
            }
        }
        __syncthreads();

        // coalesced out2 flush + re-zero R for next tile
        {
            long long fbase = E0 * 3;                // float offset, 16B-aligned
            long long nfl = ((long long)n_edges - E0) * 3;
            if (nfl >= 768) {
                if (t < 192) ((float4*)(out2 + fbase))[t] = ((const float4*)O)[t];
            } else {
                for (int i = t; i < (int)nfl; i += 256) out2[fbase + i] = O[i];
            }
            if (k + 1 < EPT)
                for (int i = t; i < 774; i += 256) R[i] = 0.f;   // disjoint from O
        }
        __syncthreads();
    }

    // ---- scan + global reservation ----
    if (t == 0) {
        unsigned a = 0;
        for (int b = 0; b < NB; ++b) { sst[b] = a; a += cnt[b]; }
        sst[NB] = a;
        stot = a;
    }
    if (t < NB && cnt[t]) bas[t] = atomicAdd(&tails[(size_t)t << 4], cnt[t]);
    __syncthreads();

    // ---- bucket-sorted staging (stg overlays R/O — all phase-A uses done) ----
#pragma unroll
    for (int k = 0; k < EPT; ++k) {
        if (posA[k] != 0xffffffffu) {
            unsigned b = payA[k].x >> WSH;
            stg[sst[b] + posA[k]] = payA[k];
        }
        if (posB[k] != 0xffffffffu) {
            unsigned b = n_win + (payB[k].x >> WSH);
            stg[sst[b] + posB[k]] = payB[k];
        }
    }
    __syncthreads();

    // ---- coalesced flush (consecutive slots -> consecutive dst) ----
    const unsigned tot = stot;
    for (unsigned i = t; i < tot; i += 256) {
        unsigned b = 0;
        while (i >= sst[b + 1]) ++b;                 // ≤14 iters
        unsigned g = bas[b] + (i - sst[b]);
        uint2 r = stg[i];
        if (g < cap) {
            rec[(size_t)b * cap + g] = r;
        } else {
            unsigned os = atomicAdd(&tails[(size_t)OVSLOT << 4], 1u);
            if (os < ocap) {
                if ((int)b >= n_win) r.x |= 0x80000000u;   // B-record flag
                ovf[os] = r;
            }
        }
    }
}

// ---------------------------------------------------------------------------
// P2 (full): each (window, slice) block reads its bucket slices exactly once.
__global__ __launch_bounds__(1024) void accum_b(
    const uint2* __restrict__ rec, const uint2* __restrict__ ovf,
    const unsigned* __restrict__ tails,
    float* __restrict__ pA, float* __restrict__ pB,
    int n_win, unsigned cap, unsigned ocap)
{
    __shared__ float tA[WSZ];
    __shared__ float tB[WSZ];

    const int w  = blockIdx.x / SLC;
    const int sl = blockIdx.x % SLC;
    const int t  = threadIdx.x;

    float4 z = make_float4(0.f, 0.f, 0.f, 0.f);
    for (int i = t; i < (WSZ >> 2); i += 1024) {
        ((float4*)tA)[i] = z; ((float4*)tB)[i] = z;
    }
    __syncthreads();

    {   // A bucket slice
        unsigned nA = min(tails[(size_t)w << 4], cap);
        const uint2* r = rec + (size_t)w * cap;
        unsigned i0 = (unsigned)((unsigned long long)nA * sl / SLC);
        unsigned i1 = (unsigned)((unsigned long long)nA * (sl + 1) / SLC);
        for (unsigned i = i0 + t; i < i1; i += 1024) {
            uint2 q = r[i];
            atomicAdd(&tA[q.x & (WSZ - 1)], __uint_as_float(q.y));
        }
    }
    {   // B bucket slice
        unsigned nB = min(tails[(size_t)(n_win + w) << 4], cap);
        const uint2* r = rec + (size_t)(n_win + w) * cap;
        unsigned i0 = (unsigned)((unsigned long long)nB * sl / SLC);
        unsigned i1 = (unsigned)((unsigned long long)nB * (sl + 1) / SLC);
        for (unsigned i = i0 + t; i < i1; i += 1024) {
            uint2 q = r[i];
            atomicAdd(&tB[q.x & (WSZ - 1)], __uint_as_float(q.y));
        }
    }
    {   // overflow arena (empty for non-adversarial inputs)
        unsigned no = min(tails[(size_t)OVSLOT << 4], ocap);
        if (no) {
            unsigned i0 = (unsigned)((unsigned long long)no * sl / SLC);
            unsigned i1 = (unsigned)((unsigned long long)no * (sl + 1) / SLC);
            for (unsigned i = i0 + t; i < i1; i += 1024) {
                uint2 q = ovf[i];
                unsigned node = q.x & 0x7fffffffu;
                if ((int)(node >> WSH) == w) {
                    if (q.x >> 31) atomicAdd(&tB[node & (WSZ - 1)], __uint_as_float(q.y));
                    else           atomicAdd(&tA[node & (WSZ - 1)], __uint_as_float(q.y));
                }
            }
        }
    }
    __syncthreads();

    // Flush: plain coalesced float4 stores — no atomics.
    float* dA = pA + ((size_t)blockIdx.x << WSH);
    float* dB = pB + ((size_t)blockIdx.x << WSH);
    for (int i = t; i < (WSZ >> 2); i += 1024) {
        ((float4*)dA)[i] = ((const float4*)tA)[i];
        ((float4*)dB)[i] = ((const float4*)tB)[i];
    }
}

// ---------------------------------------------------------------------------
// P3 (full): reduce SLC partials and compose result.
__global__ __launch_bounds__(256) void node_final_b(
    const float* __restrict__ od,
    const float* __restrict__ conc,
    const float* __restrict__ pA,
    const float* __restrict__ pB,
    float* __restrict__ out, int n_nodes)
{
    int n = blockIdx.x * blockDim.x + threadIdx.x;
    if (n >= n_nodes) return;

    const int w = n >> WSH, i = n & (WSZ - 1);
    size_t base = ((size_t)(w * SLC) << WSH) + i;
    float a0 = 0.f, a1 = 0.f, b0 = 0.f, b1 = 0.f;
#pragma unroll
    for (int sl = 0; sl < SLC; sl += 2) {
        a0 += pA[base + ((size_t)(sl + 0) << WSH)];
        a1 += pA[base + ((size_t)(sl + 1) << WSH)];
        b0 += pB[base + ((size_t)(sl + 0) << WSH)];
        b1 += pB[base + ((size_t)(sl + 1) << WSH)];
    }
    float a = a0 + a1, b = b0 + b1;

    long long bi = (long long)n * 48 + 45;
    float c  = conc[n];
    float p  = od[bi + 1];
    float is = 1.0f / od[bi + 2];

    float r = c;
    if (n != n_nodes - 1)
        r += (b - a * c) * is + 0.0052f * p * is;
    out[n] = r;
}

// ---------------------------------------------------------------------------
// Fallback path (round-5 proven): flat records + windowed scan + u64 atomics.
__global__ __launch_bounds__(256) void edge_conv_o(
    const float* __restrict__ flow, const int* __restrict__ ei,
    const float* __restrict__ conv_w, const float* __restrict__ conv_b,
    float* __restrict__ out2, int n_edges)
{
    __shared__ float w[40];
    int t = threadIdx.x;
    if (t < 36) {
        int i  = t & 3;
        int kw = (t >> 2) % 3;
        int kh = t / 12;
        w[t] = conv_w[i * 9 + kh * 3 + kw];
    }
    if (t == 36) w[36] = conv_b[0];
    __syncthreads();

    int e = blockIdx.x * blockDim.x + t;
    if (e >= n_edges) return;

    const float4* fp = (const float4*)(flow + (long long)e * 12);
    float acc = w[36];
#pragma unroll
    for (int q = 0; q < 9; ++q) {
        float4 v = fp[q];
        acc = fmaf(v.x, w[q * 4 + 0], acc);
        acc = fmaf(v.y, w[q * 4 + 1], acc);
        acc = fmaf(v.z, w[q * 4 + 2], acc);
        acc = fmaf(v.w, w[q * 4 + 3], acc);
    }

    float* o = out2 + (long long)e * 3;
    o[0] = (float)ei[e];
    o[1] = (float)ei[n_edges + e];
    o[2] = acc;
}

__global__ __launch_bounds__(1024) void accum_o(
    const float* __restrict__ out2,
    const float* __restrict__ conc,
    unsigned long long* __restrict__ acc,
    int n_edges, int n_nodes)
{
    __shared__ float tA[OWSZ];
    __shared__ float tB[OWSZ];

    const int w    = blockIdx.x / OPB;
    const int sl   = blockIdx.x % OPB;
    const int base = w << OWSH;

    for (int i = threadIdx.x; i < OWSZ; i += 1024) { tA[i] = 0.f; tB[i] = 0.f; }
    __syncthreads();

    const long long e0 = (long long)sl * n_edges / OPB;
    const long long e1 = (long long)(sl + 1) * n_edges / OPB;
    for (long long e = e0 + threadIdx.x; e < e1; e += 1024) {
        const float* r = out2 + e * 3;
        float fs = r[0], fd = r[1], v = r[2];
        int s = (int)fs, d = (int)fd;
        if (s == d) continue;
        if ((s >> OWSH) == w) atomicAdd(&tA[s - base], v);
        if ((d >> OWSH) == w) atomicAdd(&tB[d - base], v * conc[s]);
    }
    __syncthreads();

    for (int i = threadIdx.x; i < OWSZ; i += 1024) {
        int n = base + i;
        if (n >= n_nodes) continue;
        float a = tA[i], b = tB[i];
        if (a == 0.f && b == 0.f) continue;
        int qa = __float2int_rn(a * OFPS);
        int qb = __float2int_rn(b * OFPS);
        qa = min(max(qa, -OQCLMP), OQCLMP);
        qb = min(max(qb, -OQCLMP), OQCLMP);
        unsigned long long enc =
            ((unsigned long long)(unsigned)(qa + OQBIAS) << 37) +
            ((unsigned long long)(unsigned)(qb + OQBIAS) << 10) + 1ULL;
        atomicAdd(acc + n, enc);
    }
}

__global__ __launch_bounds__(256) void node_final_o(
    const float* __restrict__ od,
    const float* __restrict__ conc,
    const unsigned long long* __restrict__ acc,
    float* __restrict__ out, int n_nodes)
{
    int n = blockIdx.x * blockDim.x + threadIdx.x;
    if (n >= n_nodes) return;

    unsigned long long t = acc[n];
    long long cnt = (long long)(t & 1023ULL);
    unsigned long long t2 = t >> 10;
    long long sbr = (long long)(t2 & ((1ULL << 27) - 1));
    long long sar = (long long)(t2 >> 27);
    float a = (float)(sar - cnt * OQBIAS) * (1.0f / OFPS);
    float b = (float)(sbr - cnt * OQBIAS) * (1.0f / OFPS);

    long long bi = (long long)n * 48 + 45;
    float c  = conc[n];
    float p  = od[bi + 1];
    float is = 1.0f / od[bi + 2];

    float r = c;
    if (n != n_nodes - 1)
        r += (b - a * c) * is + 0.0052f * p * is;
    out[n] = r;
}

// ---------------------------------------------------------------------------
extern "C" void kernel_launch(void* const* d_in, const int* in_sizes, int n_in,
                              void* d_out, int out_size, void* d_ws, size_t ws_size,
                              hipStream_t stream) {
    const float* od   = (const float*)d_in[0];
    const float* flow = (const float*)d_in[1];
    const float* cw   = (const float*)d_in[2];
    const float* cb   = (const float*)d_in[3];
    const int*   ei   = (const int*)d_in[4];

    const int n_nodes = in_sizes[0] / 48;
    const int n_edges = in_sizes[4] / 2;

    float* out_res = (float*)d_out;        // (NN,)
    float* out2    = out_res + n_nodes;    // (NE,3)

    dim3 blk(256);
    dim3 grid_nodes((n_nodes + 255) / 256);

    // --- full-path workspace layout -------------------------------------
    const int n_win = (n_nodes + WSZ - 1) >> WSH;                 // 7
    const int NB    = 2 * n_win;                                  // 14
    const unsigned cap  = (unsigned)(n_edges / (n_win > 0 ? n_win : 1))
                        + (unsigned)(n_edges / 8) + 4096u;        // expected + slack
    const unsigned ocap = (unsigned)(2ULL * (unsigned long long)n_edges);

    size_t off = 0;
    size_t o_conc  = off; off += (((size_t)n_nodes * 4) + 255) & ~255ULL;
    size_t o_tails = off; off += ((OVSLOT + 1) * 16 * 4 + 255) & ~255ULL;
    size_t o_rec   = off; off += (((size_t)NB * cap * 8) + 255) & ~255ULL;
    size_t o_ovf   = off; off += (((size_t)ocap * 8) + 255) & ~255ULL;
    size_t o_pA    = off; off += (((size_t)n_win * SLC * WSZ * 4) + 255) & ~255ULL;
    size_t o_pB    = off; off += (((size_t)n_win * SLC * WSZ * 4) + 255) & ~255ULL;
    const bool full = (ws_size >= off) && (n_win <= MAXWIN);

    float* conc = (float*)((char*)d_ws + o_conc);

    if (full) {
        unsigned* tails = (unsigned*)((char*)d_ws + o_tails);
        uint2* rec = (uint2*)((char*)d_ws + o_rec);
        uint2* ovf = (uint2*)((char*)d_ws + o_ovf);
        float* pA  = (float*)((char*)d_ws + o_pA);
        float* pB  = (float*)((char*)d_ws + o_pB);

        dim3 grid_es((n_edges + 256 * EPT - 1) / (256 * EPT));    // 3125

        prep<<<grid_nodes, blk, 0, stream>>>(od, conc, nullptr, tails, n_nodes);
        edge_scatter<<<grid_es, blk, 0, stream>>>(flow, ei, cw, cb, conc,
                                                  out2, rec, ovf, tails,
                                                  n_edges, n_win, cap, ocap);
        accum_b<<<dim3(n_win * SLC), dim3(1024), 0, stream>>>(
            rec, ovf, tails, pA, pB, n_win, cap, ocap);
        node_final_b<<<grid_nodes, blk, 0, stream>>>(od, conc, pA, pB,
                                                     out_res, n_nodes);
    } else {
        // round-5 pipeline
        unsigned long long* acc =
            (unsigned long long*)((char*)d_ws + (((size_t)n_nodes * 4 + 7) / 8 * 8));
        const int n_win_o = (n_nodes + OWSZ - 1) >> OWSH;
        dim3 grid_edges((n_edges + 255) / 256);

        prep<<<grid_nodes, blk, 0, stream>>>(od, conc, acc, nullptr, n_nodes);
        edge_conv_o<<<grid_edges, blk, 0, stream>>>(flow, ei, cw, cb, out2, n_edges);
        accum_o<<<dim3(n_win_o * OPB), dim3(1024), 0, stream>>>(
            out2, conc, acc, n_edges, n_nodes);
        node_final_o<<<grid_nodes, blk, 0, stream>>>(od, conc, acc,
                                                     out_res, n_nodes);
    }
}

// Round 5
// 366.978 us; speedup vs baseline: 1.2746x; 1.2746x over previous
//
#include <hip/hip_runtime.h>

// PINNLayer — NN=100000, NE=3200000. fp32 in, fp32 out.
// d_out fp32: [ result (NN) | out2 (NE,3) rows = [src,dst,val] ].
//
// Round-10: round-4 proved the separable conv coalesces the flow reads but
// LDS-ATOMIC accumulation serializes (2.1M conflicts, 232us). Fix: the
// (row,part,r) partial-dot triple is UNIQUE -> plain ds_write, no atomics,
// no zero-init:  Pp[row*9 + r*3 + part] = dot(flow_f4[row,part], w[r,part]).
// Consumer: val[e] = b + sum_part Pp[e][0][part]+Pp[e+1][1][part]+Pp[e+2][2][part]
// (9 scalar LDS reads, stride-9 = conflict-free). 2 barriers/tile.
// Front-end transactions/wave: 432 (stride-48B re-walks) -> 48 (coalesced).
//   P1 edge_scatter: coalesced conv via LDS partials + out2 + bucket scatter.
//   P2 accum_b: 7 windows x 32 slices; every record read exactly once.
//   P3 node_final_b: reduce 32 partials + compose.
// Fallback to the proven round-5 pipeline if ws_size too small.

#define WSH    14
#define WSZ    16384    // nodes per window (128KB LDS for two fp32 tables)
#define SLC    32       // slices per window -> grid 7*32 = 224 blocks
#define EPT    4        // 256-edge tiles per block in edge_scatter
#define MAXWIN 16       // max windows supported
#define OVSLOT 32       // tail slot index for the overflow arena

// old-path constants (fallback)
#define OWSH 13
#define OWSZ 8192
#define OPB  16
#define OFPS 8192.0f
#define OQBIAS (1 << 20)
#define OQCLMP ((1 << 19) - 1)

// ---------------------------------------------------------------------------
// prep: conc gather; zero bucket tails (full path) or acc (fallback path).
__global__ __launch_bounds__(256) void prep(
    const float* __restrict__ od,
    float* __restrict__ conc,
    unsigned long long* __restrict__ acc,
    unsigned* __restrict__ tails,      // padded: tail[i] at tails[i<<4]
    int n_nodes)
{
    if (blockIdx.x == 0 && tails && threadIdx.x <= OVSLOT)
        tails[(size_t)threadIdx.x << 4] = 0u;
    int n = blockIdx.x * blockDim.x + threadIdx.x;
    if (n >= n_nodes) return;
    conc[n] = od[(long long)n * 48 + 45];   // origin_data[n,15,0]
    if (acc) acc[n] = 0ULL;
}

// ---------------------------------------------------------------------------
// P1 (full): separable conv via atomic-free LDS partials + bucket scatter.
// w[t] (t<36): t = r*12 + kw*4 + i  ->  conv_w[i*9+r*3+kw];  w[36] = bias.
// val[e] = b + sum_{j<36} flow[e*12+j]*w[j]
//        = b + P0[e] + P1[e+1] + P2[e+2],  Pr[row] = dot(flow_row, w_row_r).
// A-record {s, val} -> bucket s>>WSH;  B-record {d, val*conc[s]} -> bucket n_win+(d>>WSH)
__global__ __launch_bounds__(256) void edge_scatter(
    const float* __restrict__ flow, const int* __restrict__ ei,
    const float* __restrict__ conv_w, const float* __restrict__ conv_b,
    const float* __restrict__ conc,
    float* __restrict__ out2,
    uint2* __restrict__ rec,           // NB buckets x cap records
    uint2* __restrict__ ovf,
    unsigned* __restrict__ tails,
    int n_edges, int n_win, unsigned cap, unsigned ocap)
{
    __shared__ float    w[40];
    __shared__ unsigned cnt[2 * MAXWIN];
    __shared__ unsigned sst[2 * MAXWIN + 1];   // exclusive scan + total sentinel
    __shared__ unsigned bas[2 * MAXWIN];       // global reservation base
    __shared__ unsigned stot;
    // phase A: Pp[258*9] partial dots (9288B); phase B: stg[2048] recs (16KB)
    __shared__ __align__(16) char smem[16384];
    float* Pp  = (float*)smem;
    uint2* stg = (uint2*)smem;

    const int t  = threadIdx.x;
    const int NB = 2 * n_win;
    if (t < 36) {
        int i  = t & 3;
        int kw = (t >> 2) % 3;
        int r  = t / 12;
        w[t] = conv_w[i * 9 + r * 3 + kw];
    }
    if (t == 36) w[36] = conv_b[0];
    if (t < 2 * MAXWIN) cnt[t] = 0u;
    __syncthreads();

    uint2    payA[EPT], payB[EPT];
    unsigned posA[EPT], posB[EPT];
#pragma unroll
    for (int k = 0; k < EPT; ++k) { posA[k] = 0xffffffffu; posB[k] = 0xffffffffu; }

    // ---- per-tile: coalesced conv (atomic-free LDS partials) + out2 + hist ----
#pragma unroll
    for (int k = 0; k < EPT; ++k) {
        const long long E0 = (long long)blockIdx.x * (256 * EPT) + (long long)k * 256;
        if (E0 >= n_edges) break;
        const int nrows = (int)(((long long)n_edges + 2 - E0) < 258 ?
                                ((long long)n_edges + 2 - E0) : 258);
        const int nf4 = 3 * nrows;

        // coalesced flow read: thread i loads float4 #i of the tile (ONE touch);
        // 3 partial dots -> 3 plain ds_writes at UNIQUE addresses.
        const float4* fb = (const float4*)flow + E0 * 3;
        for (int i = t; i < nf4; i += 256) {
            float4 v = fb[i];
            int row  = i / 3;
            int part = i - row * 3;
            int kk   = part << 2;                    // 0,4,8
            float d0 = fmaf(v.x, w[kk +  0], fmaf(v.y, w[kk +  1],
                       fmaf(v.z, w[kk +  2], v.w * w[kk +  3])));
            float d1 = fmaf(v.x, w[kk + 12], fmaf(v.y, w[kk + 13],
                       fmaf(v.z, w[kk + 14], v.w * w[kk + 15])));
            float d2 = fmaf(v.x, w[kk + 24], fmaf(v.y, w[kk + 25],
                       fmaf(v.z, w[kk + 26], v.w * w[kk + 27])));
            int b = row * 9 + part;
            Pp[b + 0] = d0;                          // r=0
            Pp[b + 3] = d1;                          // r=1
            Pp[b + 6] = d2;                          // r=2
        }
        __syncthreads();

        const long long e = E0 + t;
        if (e < n_edges) {
            const int b = t * 9;
            float val = w[36]
                + (Pp[b +  0] + Pp[b +  1] + Pp[b +  2])      // P0[t]
                + (Pp[b + 12] + Pp[b + 13] + Pp[b + 14])      // P1[t+1]
                + (Pp[b + 24] + Pp[b + 25] + Pp[b + 26]);     // P2[t+2]
            int s = ei[e];
            int d = ei[n_edges + e];
            float cs = conc[s];                      // L2-resident gather (400KB)
            float* o = out2 + e * 3;
            o[0] = (float)s;
            o[1] = (float)d;
            o[2] = val;
            if (s != d) {
                payA[k].x = (unsigned)s; payA[k].y = __float_as_uint(val);
                payB[k].x = (unsigned)d; payB[k].y = __float_as_uint(val * cs);
                posA[k] = atomicAdd(&cnt[(unsigned)s >> WSH], 1u);
                posB[k] = atomicAdd(&cnt[n_win + ((unsigned)d >> WSH)], 1u);
            }
        }
        __syncthreads();                             // Pp reused next tile
    }

    // ---- scan + global reservation ----
    if (t == 0) {
        unsigned a = 0;
        for (int b = 0; b < NB; ++b) { sst[b] = a; a += cnt[b]; }
        sst[NB] = a;
        stot = a;
    }
    if (t < NB && cnt[t]) bas[t] = atomicAdd(&tails[(size_t)t << 4], cnt[t]);
    __syncthreads();

    // ---- bucket-sorted staging (stg overlays Pp — all phase-A uses done) ----
#pragma unroll
    for (int k = 0; k < EPT; ++k) {
        if (posA[k] != 0xffffffffu) {
            unsigned b = payA[k].x >> WSH;
            stg[sst[b] + posA[k]] = payA[k];
        }
        if (posB[k] != 0xffffffffu) {
            unsigned b = n_win + (payB[k].x >> WSH);
            stg[sst[b] + posB[k]] = payB[k];
        }
    }
    __syncthreads();

    // ---- coalesced flush (consecutive slots -> consecutive dst) ----
    const unsigned tot = stot;
    for (unsigned i = t; i < tot; i += 256) {
        unsigned b = 0;
        while (i >= sst[b + 1]) ++b;                 // ≤14 iters
        unsigned g = bas[b] + (i - sst[b]);
        uint2 r = stg[i];
        if (g < cap) {
            rec[(size_t)b * cap + g] = r;
        } else {
            unsigned os = atomicAdd(&tails[(size_t)OVSLOT << 4], 1u);
            if (os < ocap) {
                if ((int)b >= n_win) r.x |= 0x80000000u;   // B-record flag
                ovf[os] = r;
            }
        }
    }
}

// ---------------------------------------------------------------------------
// P2 (full): each (window, slice) block reads its bucket slices exactly once.
__global__ __launch_bounds__(1024) void accum_b(
    const uint2* __restrict__ rec, const uint2* __restrict__ ovf,
    const unsigned* __restrict__ tails,
    float* __restrict__ pA, float* __restrict__ pB,
    int n_win, unsigned cap, unsigned ocap)
{
    __shared__ float tA[WSZ];
    __shared__ float tB[WSZ];

    const int w  = blockIdx.x / SLC;
    const int sl = blockIdx.x % SLC;
    const int t  = threadIdx.x;

    float4 z = make_float4(0.f, 0.f, 0.f, 0.f);
    for (int i = t; i < (WSZ >> 2); i += 1024) {
        ((float4*)tA)[i] = z; ((float4*)tB)[i] = z;
    }
    __syncthreads();

    {   // A bucket slice
        unsigned nA = min(tails[(size_t)w << 4], cap);
        const uint2* r = rec + (size_t)w * cap;
        unsigned i0 = (unsigned)((unsigned long long)nA * sl / SLC);
        unsigned i1 = (unsigned)((unsigned long long)nA * (sl + 1) / SLC);
        for (unsigned i = i0 + t; i < i1; i += 1024) {
            uint2 q = r[i];
            atomicAdd(&tA[q.x & (WSZ - 1)], __uint_as_float(q.y));
        }
    }
    {   // B bucket slice
        unsigned nB = min(tails[(size_t)(n_win + w) << 4], cap);
        const uint2* r = rec + (size_t)(n_win + w) * cap;
        unsigned i0 = (unsigned)((unsigned long long)nB * sl / SLC);
        unsigned i1 = (unsigned)((unsigned long long)nB * (sl + 1) / SLC);
        for (unsigned i = i0 + t; i < i1; i += 1024) {
            uint2 q = r[i];
            atomicAdd(&tB[q.x & (WSZ - 1)], __uint_as_float(q.y));
        }
    }
    {   // overflow arena (empty for non-adversarial inputs)
        unsigned no = min(tails[(size_t)OVSLOT << 4], ocap);
        if (no) {
            unsigned i0 = (unsigned)((unsigned long long)no * sl / SLC);
            unsigned i1 = (unsigned)((unsigned long long)no * (sl + 1) / SLC);
            for (unsigned i = i0 + t; i < i1; i += 1024) {
                uint2 q = ovf[i];
                unsigned node = q.x & 0x7fffffffu;
                if ((int)(node >> WSH) == w) {
                    if (q.x >> 31) atomicAdd(&tB[node & (WSZ - 1)], __uint_as_float(q.y));
                    else           atomicAdd(&tA[node & (WSZ - 1)], __uint_as_float(q.y));
                }
            }
        }
    }
    __syncthreads();

    // Flush: plain coalesced float4 stores — no atomics.
    float* dA = pA + ((size_t)blockIdx.x << WSH);
    float* dB = pB + ((size_t)blockIdx.x << WSH);
    for (int i = t; i < (WSZ >> 2); i += 1024) {
        ((float4*)dA)[i] = ((const float4*)tA)[i];
        ((float4*)dB)[i] = ((const float4*)tB)[i];
    }
}

// ---------------------------------------------------------------------------
// P3 (full): reduce SLC partials and compose result.
__global__ __launch_bounds__(256) void node_final_b(
    const float* __restrict__ od,
    const float* __restrict__ conc,
    const float* __restrict__ pA,
    const float* __restrict__ pB,
    float* __restrict__ out, int n_nodes)
{
    int n = blockIdx.x * blockDim.x + threadIdx.x;
    if (n >= n_nodes) return;

    const int w = n >> WSH, i = n & (WSZ - 1);
    size_t base = ((size_t)(w * SLC) << WSH) + i;
    float a0 = 0.f, a1 = 0.f, b0 = 0.f, b1 = 0.f;
#pragma unroll
    for (int sl = 0; sl < SLC; sl += 2) {
        a0 += pA[base + ((size_t)(sl + 0) << WSH)];
        a1 += pA[base + ((size_t)(sl + 1) << WSH)];
        b0 += pB[base + ((size_t)(sl + 0) << WSH)];
        b1 += pB[base + ((size_t)(sl + 1) << WSH)];
    }
    float a = a0 + a1, b = b0 + b1;

    long long bi = (long long)n * 48 + 45;
    float c  = conc[n];
    float p  = od[bi + 1];
    float is = 1.0f / od[bi + 2];

    float r = c;
    if (n != n_nodes - 1)
        r += (b - a * c) * is + 0.0052f * p * is;
    out[n] = r;
}

// ---------------------------------------------------------------------------
// Fallback path (round-5 proven): flat records + windowed scan + u64 atomics.
__global__ __launch_bounds__(256) void edge_conv_o(
    const float* __restrict__ flow, const int* __restrict__ ei,
    const float* __restrict__ conv_w, const float* __restrict__ conv_b,
    float* __restrict__ out2, int n_edges)
{
    __shared__ float w[40];
    int t = threadIdx.x;
    if (t < 36) {
        int i  = t & 3;
        int kw = (t >> 2) % 3;
        int kh = t / 12;
        w[t] = conv_w[i * 9 + kh * 3 + kw];
    }
    if (t == 36) w[36] = conv_b[0];
    __syncthreads();

    int e = blockIdx.x * blockDim.x + t;
    if (e >= n_edges) return;

    const float4* fp = (const float4*)(flow + (long long)e * 12);
    float acc = w[36];
#pragma unroll
    for (int q = 0; q < 9; ++q) {
        float4 v = fp[q];
        acc = fmaf(v.x, w[q * 4 + 0], acc);
        acc = fmaf(v.y, w[q * 4 + 1], acc);
        acc = fmaf(v.z, w[q * 4 + 2], acc);
        acc = fmaf(v.w, w[q * 4 + 3], acc);
    }

    float* o = out2 + (long long)e * 3;
    o[0] = (float)ei[e];
    o[1] = (float)ei[n_edges + e];
    o[2] = acc;
}

__global__ __launch_bounds__(1024) void accum_o(
    const float* __restrict__ out2,
    const float* __restrict__ conc,
    unsigned long long* __restrict__ acc,
    int n_edges, int n_nodes)
{
    __shared__ float tA[OWSZ];
    __shared__ float tB[OWSZ];

    const int w    = blockIdx.x / OPB;
    const int sl   = blockIdx.x % OPB;
    const int base = w << OWSH;

    for (int i = threadIdx.x; i < OWSZ; i += 1024) { tA[i] = 0.f; tB[i] = 0.f; }
    __syncthreads();

    const long long e0 = (long long)sl * n_edges / OPB;
    const long long e1 = (long long)(sl + 1) * n_edges / OPB;
    for (long long e = e0 + threadIdx.x; e < e1; e += 1024) {
        const float* r = out2 + e * 3;
        float fs = r[0], fd = r[1], v = r[2];
        int s = (int)fs, d = (int)fd;
        if (s == d) continue;
        if ((s >> OWSH) == w) atomicAdd(&tA[s - base], v);
        if ((d >> OWSH) == w) atomicAdd(&tB[d - base], v * conc[s]);
    }
    __syncthreads();

    for (int i = threadIdx.x; i < OWSZ; i += 1024) {
        int n = base + i;
        if (n >= n_nodes) continue;
        float a = tA[i], b = tB[i];
        if (a == 0.f && b == 0.f) continue;
        int qa = __float2int_rn(a * OFPS);
        int qb = __float2int_rn(b * OFPS);
        qa = min(max(qa, -OQCLMP), OQCLMP);
        qb = min(max(qb, -OQCLMP), OQCLMP);
        unsigned long long enc =
            ((unsigned long long)(unsigned)(qa + OQBIAS) << 37) +
            ((unsigned long long)(unsigned)(qb + OQBIAS) << 10) + 1ULL;
        atomicAdd(acc + n, enc);
    }
}

__global__ __launch_bounds__(256) void node_final_o(
    const float* __restrict__ od,
    const float* __restrict__ conc,
    const unsigned long long* __restrict__ acc,
    float* __restrict__ out, int n_nodes)
{
    int n = blockIdx.x * blockDim.x + threadIdx.x;
    if (n >= n_nodes) return;

    unsigned long long t = acc[n];
    long long cnt = (long long)(t & 1023ULL);
    unsigned long long t2 = t >> 10;
    long long sbr = (long long)(t2 & ((1ULL << 27) - 1));
    long long sar = (long long)(t2 >> 27);
    float a = (float)(sar - cnt * OQBIAS) * (1.0f / OFPS);
    float b = (float)(sbr - cnt * OQBIAS) * (1.0f / OFPS);

    long long bi = (long long)n * 48 + 45;
    float c  = conc[n];
    float p  = od[bi + 1];
    float is = 1.0f / od[bi + 2];

    float r = c;
    if (n != n_nodes - 1)
        r += (b - a * c) * is + 0.0052f * p * is;
    out[n] = r;
}

// ---------------------------------------------------------------------------
extern "C" void kernel_launch(void* const* d_in, const int* in_sizes, int n_in,
                              void* d_out, int out_size, void* d_ws, size_t ws_size,
                              hipStream_t stream) {
    const float* od   = (const float*)d_in[0];
    const float* flow = (const float*)d_in[1];
    const float* cw   = (const float*)d_in[2];
    const float* cb   = (const float*)d_in[3];
    const int*   ei   = (const int*)d_in[4];

    const int n_nodes = in_sizes[0] / 48;
    const int n_edges = in_sizes[4] / 2;

    float* out_res = (float*)d_out;        // (NN,)
    float* out2    = out_res + n_nodes;    // (NE,3)

    dim3 blk(256);
    dim3 grid_nodes((n_nodes + 255) / 256);

    // --- full-path workspace layout -------------------------------------
    const int n_win = (n_nodes + WSZ - 1) >> WSH;                 // 7
    const int NB    = 2 * n_win;                                  // 14
    const unsigned cap  = (unsigned)(n_edges / (n_win > 0 ? n_win : 1))
                        + (unsigned)(n_edges / 8) + 4096u;        // expected + slack
    const unsigned ocap = (unsigned)(2ULL * (unsigned long long)n_edges);

    size_t off = 0;
    size_t o_conc  = off; off += (((size_t)n_nodes * 4) + 255) & ~255ULL;
    size_t o_tails = off; off += ((OVSLOT + 1) * 16 * 4 + 255) & ~255ULL;
    size_t o_rec   = off; off += (((size_t)NB * cap * 8) + 255) & ~255ULL;
    size_t o_ovf   = off; off += (((size_t)ocap * 8) + 255) & ~255ULL;
    size_t o_pA    = off; off += (((size_t)n_win * SLC * WSZ * 4) + 255) & ~255ULL;
    size_t o_pB    = off; off += (((size_t)n_win * SLC * WSZ * 4) + 255) & ~255ULL;
    const bool full = (ws_size >= off) && (n_win <= MAXWIN);

    float* conc = (float*)((char*)d_ws + o_conc);

    if (full) {
        unsigned* tails = (unsigned*)((char*)d_ws + o_tails);
        uint2* rec = (uint2*)((char*)d_ws + o_rec);
        uint2* ovf = (uint2*)((char*)d_ws + o_ovf);
        float* pA  = (float*)((char*)d_ws + o_pA);
        float* pB  = (float*)((char*)d_ws + o_pB);

        dim3 grid_es((n_edges + 256 * EPT - 1) / (256 * EPT));    // 3125

        prep<<<grid_nodes, blk, 0, stream>>>(od, conc, nullptr, tails, n_nodes);
        edge_scatter<<<grid_es, blk, 0, stream>>>(flow, ei, cw, cb, conc,
                                                  out2, rec, ovf, tails,
                                                  n_edges, n_win, cap, ocap);
        accum_b<<<dim3(n_win * SLC), dim3(1024), 0, stream>>>(
            rec, ovf, tails, pA, pB, n_win, cap, ocap);
        node_final_b<<<grid_nodes, blk, 0, stream>>>(od, conc, pA, pB,
                                                     out_res, n_nodes);
    } else {
        // round-5 pipeline
        unsigned long long* acc =
            (unsigned long long*)((char*)d_ws + (((size_t)n_nodes * 4 + 7) / 8 * 8));
        const int n_win_o = (n_nodes + OWSZ - 1) >> OWSH;
        dim3 grid_edges((n_edges + 255) / 256);

        prep<<<grid_nodes, blk, 0, stream>>>(od, conc, acc, nullptr, n_nodes);
        edge_conv_o<<<grid_edges, blk, 0, stream>>>(flow, ei, cw, cb, out2, n_edges);
        accum_o<<<dim3(n_win_o * OPB), dim3(1024), 0, stream>>>(
            out2, conc, acc, n_edges, n_nodes);
        node_final_o<<<grid_nodes, blk, 0, stream>>>(od, conc, acc,
                                                     out_res, n_nodes);
    }
}

// Round 6
// 366.873 us; speedup vs baseline: 1.2750x; 1.0003x over previous
//
#include <hip/hip_runtime.h>

// PINNLayer — NN=100000, NE=3200000. fp32 in, fp32 out.
// d_out fp32: [ result (NN) | out2 (NE,3) rows = [src,dst,val] ].
//
// Round-11 (consolidation): rounds 2-5 proved every structural redesign of
// the edge front-end (per-window scatter 344us, LDS-atomic separable 468us,
// atomic-free separable 367us) loses to round-1's simple pipeline (326us).
// r5 falsified the L1-amplification theory: coalesced flow reads made it
// SLOWER (LDS histogram same-address atomics + barriers dominate). So:
// restore round-1 exactly and polish the two kernels that hid below the
// profiler cutoff:
//   - node_final_f: 64 scalar stride-458KB loads/node -> float4 x 4 nodes/
//     thread (4x fewer load instrs, fully coalesced).
//   - edge_conv: EPT=2 + hoisted ei/conc loads (2x independent loads in
//     flight per thread).
//   P1 edge_conv: conv + out2 + bc[e]=val*conc[src].
//   P2 accum_f: 7 windows x 16384 nodes (128KB LDS) x 32 slices; 4-way
//      batched scan; plain float4 partial stores; XCD co-location swizzle.
//   P3 node_final_f: vectorized reduce of 32 partials + compose.
// Fallback to the proven round-5 pipeline if ws_size too small.

#define WSH  14
#define WSZ  16384      // nodes per window (128KB LDS for two fp32 tables)
#define PBF  32         // record slices (multiple of 8 for the XCD swizzle)

// old-path constants (fallback)
#define OWSH 13
#define OWSZ 8192
#define OPB  16
#define OFPS 8192.0f
#define OQBIAS (1 << 20)
#define OQCLMP ((1 << 19) - 1)

// ---------------------------------------------------------------------------
__global__ __launch_bounds__(256) void prep(
    const float* __restrict__ od,
    float* __restrict__ conc,
    unsigned long long* __restrict__ acc,
    int n_nodes)
{
    int n = blockIdx.x * blockDim.x + threadIdx.x;
    if (n >= n_nodes) return;
    conc[n] = od[(long long)n * 48 + 45];   // origin_data[n,15,0]
    if (acc) acc[n] = 0ULL;
}

// ---------------------------------------------------------------------------
// P1: conv + out2 + bc = val*conc[src].  EPT=2 for doubled load ILP.
__global__ __launch_bounds__(256) void edge_conv(
    const float* __restrict__ flow, const int* __restrict__ ei,
    const float* __restrict__ conv_w, const float* __restrict__ conv_b,
    const float* __restrict__ conc,
    float* __restrict__ out2, float* __restrict__ bcv, int n_edges)
{
    __shared__ float w[40];
    int t = threadIdx.x;
    if (t < 36) {
        int i  = t & 3;
        int kw = (t >> 2) % 3;
        int kh = t / 12;
        w[t] = conv_w[i * 9 + kh * 3 + kw];
    }
    if (t == 36) w[36] = conv_b[0];
    __syncthreads();

    const long long e0 = (long long)blockIdx.x * 512 + t;
    const long long e1 = e0 + 256;
    const bool v0 = e0 < n_edges;
    const bool v1 = e1 < n_edges;

    int s0 = 0, d0 = 0, s1 = 0, d1 = 0;
    if (v0) { s0 = ei[e0]; d0 = ei[n_edges + e0]; }
    if (v1) { s1 = ei[e1]; d1 = ei[n_edges + e1]; }
    float cs0 = v0 ? conc[s0] : 0.f;       // L2-resident gather (400KB)
    float cs1 = v1 ? conc[s1] : 0.f;

    const float4* f0 = (const float4*)(flow + e0 * 12);
    const float4* f1 = (const float4*)(flow + e1 * 12);
    float a0 = w[36], a1 = w[36];
#pragma unroll
    for (int q = 0; q < 9; ++q) {
        if (v0) {
            float4 v = f0[q];
            a0 = fmaf(v.x, w[q * 4 + 0], a0);
            a0 = fmaf(v.y, w[q * 4 + 1], a0);
            a0 = fmaf(v.z, w[q * 4 + 2], a0);
            a0 = fmaf(v.w, w[q * 4 + 3], a0);
        }
    }
#pragma unroll
    for (int q = 0; q < 9; ++q) {
        if (v1) {
            float4 v = f1[q];
            a1 = fmaf(v.x, w[q * 4 + 0], a1);
            a1 = fmaf(v.y, w[q * 4 + 1], a1);
            a1 = fmaf(v.z, w[q * 4 + 2], a1);
            a1 = fmaf(v.w, w[q * 4 + 3], a1);
        }
    }

    if (v0) {
        float* o = out2 + e0 * 3;
        o[0] = (float)s0; o[1] = (float)d0; o[2] = a0;
        bcv[e0] = a0 * cs0;
    }
    if (v1) {
        float* o = out2 + e1 * 3;
        o[0] = (float)s1; o[1] = (float)d1; o[2] = a1;
        bcv[e1] = a1 * cs1;
    }
}

// ---------------------------------------------------------------------------
// P2: windowed LDS accumulation (round-1 verbatim — proven).
__global__ __launch_bounds__(1024) void accum_f(
    const float* __restrict__ out2,
    const float* __restrict__ bcv,
    float* __restrict__ pA,
    float* __restrict__ pB,
    int n_edges, int n_win, int stride)
{
    __shared__ float tA[WSZ];
    __shared__ float tB[WSZ];

    const int xcd = blockIdx.x & 7;
    const int i   = blockIdx.x >> 3;
    const int j   = i / n_win;                 // 0 .. PBF/8-1
    const int sl  = xcd * (PBF >> 3) + j;      // slice id
    const int w   = i - j * n_win;             // window id

    const int t = threadIdx.x;
    for (int k = t; k < WSZ; k += 1024) { tA[k] = 0.f; tB[k] = 0.f; }
    __syncthreads();

    const long long e0 = (long long)sl * n_edges / PBF;
    const long long e1 = (long long)(sl + 1) * n_edges / PBF;

#define PROC(fs, fd, vv, bb)                                          \
    {                                                                  \
        int s_ = (int)(fs), d_ = (int)(fd);                            \
        if (s_ != d_) {                                                \
            if ((s_ >> WSH) == w) atomicAdd(&tA[s_ & (WSZ - 1)], (vv));\
            if ((d_ >> WSH) == w) atomicAdd(&tB[d_ & (WSZ - 1)], (bb));\
        }                                                              \
    }

    long long e = e0 + t;
    for (; e + 3 * 1024 < e1; e += 4 * 1024) {
        const float* r  = out2 + e * 3;
        const float* bb = bcv + e;
        float fs0 = r[0],    fd0 = r[1],    v0 = r[2];
        float fs1 = r[3072], fd1 = r[3073], v1 = r[3074];
        float fs2 = r[6144], fd2 = r[6145], v2 = r[6146];
        float fs3 = r[9216], fd3 = r[9217], v3 = r[9218];
        float b0 = bb[0], b1 = bb[1024], b2 = bb[2048], b3 = bb[3072];
        PROC(fs0, fd0, v0, b0);
        PROC(fs1, fd1, v1, b1);
        PROC(fs2, fd2, v2, b2);
        PROC(fs3, fd3, v3, b3);
    }
    for (; e < e1; e += 1024) {
        const float* r = out2 + e * 3;
        float fs = r[0], fd = r[1], vv = r[2];
        float bb = bcv[e];
        PROC(fs, fd, vv, bb);
    }
#undef PROC
    __syncthreads();

    float* dA = pA + (long long)sl * stride + ((long long)w << WSH);
    float* dB = pB + (long long)sl * stride + ((long long)w << WSH);
    for (int k = t; k < (WSZ >> 2); k += 1024) {
        ((float4*)dA)[k] = ((const float4*)tA)[k];
        ((float4*)dB)[k] = ((const float4*)tB)[k];
    }
}

// ---------------------------------------------------------------------------
// P3: vectorized reduce of PBF partials (4 nodes/thread, float4) + compose.
__global__ __launch_bounds__(256) void node_final_f(
    const float* __restrict__ od,
    const float* __restrict__ conc,
    const float* __restrict__ pA,
    const float* __restrict__ pB,
    float* __restrict__ out, int n_nodes, int stride)
{
    const int n0 = (blockIdx.x * 256 + threadIdx.x) * 4;
    if (n0 >= n_nodes) return;

    if (n0 + 4 <= n_nodes) {
        float4 a = make_float4(0.f, 0.f, 0.f, 0.f);
        float4 b = make_float4(0.f, 0.f, 0.f, 0.f);
#pragma unroll 8
        for (int sl = 0; sl < PBF; ++sl) {
            float4 va = *(const float4*)(pA + (size_t)sl * stride + n0);
            float4 vb = *(const float4*)(pB + (size_t)sl * stride + n0);
            a.x += va.x; a.y += va.y; a.z += va.z; a.w += va.w;
            b.x += vb.x; b.y += vb.y; b.z += vb.z; b.w += vb.w;
        }
        float4 c4 = *(const float4*)(conc + n0);
        float av[4] = {a.x, a.y, a.z, a.w};
        float bv[4] = {b.x, b.y, b.z, b.w};
        float cv[4] = {c4.x, c4.y, c4.z, c4.w};
        float rv[4];
#pragma unroll
        for (int j = 0; j < 4; ++j) {
            int n = n0 + j;
            long long bi = (long long)n * 48 + 45;
            float p  = od[bi + 1];
            float is = 1.0f / od[bi + 2];
            float r = cv[j];
            if (n != n_nodes - 1)
                r += (bv[j] - av[j] * cv[j]) * is + 0.0052f * p * is;
            rv[j] = r;
        }
        *(float4*)(out + n0) = make_float4(rv[0], rv[1], rv[2], rv[3]);
    } else {
        for (int n = n0; n < n_nodes; ++n) {
            float a = 0.f, b = 0.f;
#pragma unroll 8
            for (int sl = 0; sl < PBF; ++sl) {
                a += pA[(size_t)sl * stride + n];
                b += pB[(size_t)sl * stride + n];
            }
            long long bi = (long long)n * 48 + 45;
            float c  = conc[n];
            float p  = od[bi + 1];
            float is = 1.0f / od[bi + 2];
            float r = c;
            if (n != n_nodes - 1)
                r += (b - a * c) * is + 0.0052f * p * is;
            out[n] = r;
        }
    }
}

// ---------------------------------------------------------------------------
// Fallback path (round-5 proven): flat records + windowed scan + u64 atomics.
__global__ __launch_bounds__(256) void edge_conv_o(
    const float* __restrict__ flow, const int* __restrict__ ei,
    const float* __restrict__ conv_w, const float* __restrict__ conv_b,
    float* __restrict__ out2, int n_edges)
{
    __shared__ float w[40];
    int t = threadIdx.x;
    if (t < 36) {
        int i  = t & 3;
        int kw = (t >> 2) % 3;
        int kh = t / 12;
        w[t] = conv_w[i * 9 + kh * 3 + kw];
    }
    if (t == 36) w[36] = conv_b[0];
    __syncthreads();

    int e = blockIdx.x * blockDim.x + t;
    if (e >= n_edges) return;

    const float4* fp = (const float4*)(flow + (long long)e * 12);
    float acc = w[36];
#pragma unroll
    for (int q = 0; q < 9; ++q) {
        float4 v = fp[q];
        acc = fmaf(v.x, w[q * 4 + 0], acc);
        acc = fmaf(v.y, w[q * 4 + 1], acc);
        acc = fmaf(v.z, w[q * 4 + 2], acc);
        acc = fmaf(v.w, w[q * 4 + 3], acc);
    }

    float* o = out2 + (long long)e * 3;
    o[0] = (float)ei[e];
    o[1] = (float)ei[n_edges + e];
    o[2] = acc;
}

__global__ __launch_bounds__(1024) void accum_o(
    const float* __restrict__ out2,
    const float* __restrict__ conc,
    unsigned long long* __restrict__ acc,
    int n_edges, int n_nodes)
{
    __shared__ float tA[OWSZ];
    __shared__ float tB[OWSZ];

    const int w    = blockIdx.x / OPB;
    const int sl   = blockIdx.x % OPB;
    const int base = w << OWSH;

    for (int i = threadIdx.x; i < OWSZ; i += 1024) { tA[i] = 0.f; tB[i] = 0.f; }
    __syncthreads();

    const long long e0 = (long long)sl * n_edges / OPB;
    const long long e1 = (long long)(sl + 1) * n_edges / OPB;
    for (long long e = e0 + threadIdx.x; e < e1; e += 1024) {
        const float* r = out2 + e * 3;
        float fs = r[0], fd = r[1], v = r[2];
        int s = (int)fs, d = (int)fd;
        if (s == d) continue;
        if ((s >> OWSH) == w) atomicAdd(&tA[s - base], v);
        if ((d >> OWSH) == w) atomicAdd(&tB[d - base], v * conc[s]);
    }
    __syncthreads();

    for (int i = threadIdx.x; i < OWSZ; i += 1024) {
        int n = base + i;
        if (n >= n_nodes) continue;
        float a = tA[i], b = tB[i];
        if (a == 0.f && b == 0.f) continue;
        int qa = __float2int_rn(a * OFPS);
        int qb = __float2int_rn(b * OFPS);
        qa = min(max(qa, -OQCLMP), OQCLMP);
        qb = min(max(qb, -OQCLMP), OQCLMP);
        unsigned long long enc =
            ((unsigned long long)(unsigned)(qa + OQBIAS) << 37) +
            ((unsigned long long)(unsigned)(qb + OQBIAS) << 10) + 1ULL;
        atomicAdd(acc + n, enc);
    }
}

__global__ __launch_bounds__(256) void node_final_o(
    const float* __restrict__ od,
    const float* __restrict__ conc,
    const unsigned long long* __restrict__ acc,
    float* __restrict__ out, int n_nodes)
{
    int n = blockIdx.x * blockDim.x + threadIdx.x;
    if (n >= n_nodes) return;

    unsigned long long t = acc[n];
    long long cnt = (long long)(t & 1023ULL);
    unsigned long long t2 = t >> 10;
    long long sbr = (long long)(t2 & ((1ULL << 27) - 1));
    long long sar = (long long)(t2 >> 27);
    float a = (float)(sar - cnt * OQBIAS) * (1.0f / OFPS);
    float b = (float)(sbr - cnt * OQBIAS) * (1.0f / OFPS);

    long long bi = (long long)n * 48 + 45;
    float c  = conc[n];
    float p  = od[bi + 1];
    float is = 1.0f / od[bi + 2];

    float r = c;
    if (n != n_nodes - 1)
        r += (b - a * c) * is + 0.0052f * p * is;
    out[n] = r;
}

// ---------------------------------------------------------------------------
extern "C" void kernel_launch(void* const* d_in, const int* in_sizes, int n_in,
                              void* d_out, int out_size, void* d_ws, size_t ws_size,
                              hipStream_t stream) {
    const float* od   = (const float*)d_in[0];
    const float* flow = (const float*)d_in[1];
    const float* cw   = (const float*)d_in[2];
    const float* cb   = (const float*)d_in[3];
    const int*   ei   = (const int*)d_in[4];

    const int n_nodes = in_sizes[0] / 48;
    const int n_edges = in_sizes[4] / 2;

    float* out_res = (float*)d_out;        // (NN,)
    float* out2    = out_res + n_nodes;    // (NE,3)

    dim3 blk(256);
    dim3 grid_nodes((n_nodes + 255) / 256);

    // --- full-path workspace layout (round-1) ---------------------------
    const int n_win  = (n_nodes + WSZ - 1) >> WSH;     // 7
    const int stride = n_win << WSH;                   // padded node count
    size_t off = 0;
    size_t o_conc = off; off += (((size_t)n_nodes * 4) + 255) & ~255ULL;
    size_t o_bc   = off; off += (((size_t)n_edges * 4) + 255) & ~255ULL;
    size_t o_pA   = off; off += (((size_t)PBF * stride * 4) + 255) & ~255ULL;
    size_t o_pB   = off; off += (((size_t)PBF * stride * 4) + 255) & ~255ULL;
    const bool full = (ws_size >= off);

    float* conc = (float*)((char*)d_ws + o_conc);

    if (full) {
        float* bcv = (float*)((char*)d_ws + o_bc);
        float* pA  = (float*)((char*)d_ws + o_pA);
        float* pB  = (float*)((char*)d_ws + o_pB);

        dim3 grid_ec((n_edges + 511) / 512);           // EPT=2
        dim3 grid_nf(((n_nodes + 3) / 4 + 255) / 256);

        prep<<<grid_nodes, blk, 0, stream>>>(od, conc, nullptr, n_nodes);
        edge_conv<<<grid_ec, blk, 0, stream>>>(flow, ei, cw, cb, conc,
                                               out2, bcv, n_edges);
        accum_f<<<dim3(n_win * PBF), dim3(1024), 0, stream>>>(
            out2, bcv, pA, pB, n_edges, n_win, stride);
        node_final_f<<<grid_nf, blk, 0, stream>>>(od, conc, pA, pB,
                                                  out_res, n_nodes, stride);
    } else {
        // round-5 pipeline
        unsigned long long* acc =
            (unsigned long long*)((char*)d_ws + (((size_t)n_nodes * 4 + 7) / 8 * 8));
        const int n_win_o = (n_nodes + OWSZ - 1) >> OWSH;
        dim3 grid_edges((n_edges + 255) / 256);

        prep<<<grid_nodes, blk, 0, stream>>>(od, conc, acc, n_nodes);
        edge_conv_o<<<grid_edges, blk, 0, stream>>>(flow, ei, cw, cb, out2, n_edges);
        accum_o<<<dim3(n_win_o * OPB), dim3(1024), 0, stream>>>(
            out2, conc, acc, n_edges, n_nodes);
        node_final_o<<<grid_nodes, blk, 0, stream>>>(od, conc, acc,
                                                     out_res, n_nodes);
    }
}

// Round 7
// 327.008 us; speedup vs baseline: 1.4304x; 1.1219x over previous
//
#include <hip/hip_runtime.h>

// PINNLayer — NN=100000, NE=3200000. fp32 in, fp32 out.
// d_out fp32: [ result (NN) | out2 (NE,3) rows = [src,dst,val] ].
//
// Round-12: r6 proved predicated EPT=2 kills load pipelining (VGPR 16,
// VALU 4%, 124us). r1's simple conv (~85us) is floor-limited by L1-port
// amplification: flow is a SLIDING WINDOW (edge e reads rows e..e+2), so
// 9 float4 loads at 48B lane stride re-touch the same lines 9x (~432 line
// transactions/wave ~= 1.84GB through L1). Fix WITHOUT the failed r4/r5
// machinery (their cost was histogram atomics + extra barriers, not LDS):
//   edge_conv: stage the block's 258-row tile global->LDS with consecutive
//   coalesced float4 loads (each line fetched ONCE: ~194 lines/block), one
//   barrier, zero LDS atomics; conv reads stride-3-f4 from LDS (keeps all
//   32 banks saturated -> throughput-conflict-free for ds_read_b128).
//   P1 edge_conv: LDS-tiled conv + out2 + bc[e]=val*conc[src].
//   P2 accum_f: 7 windows x 16384 nodes (128KB LDS) x 32 slices (r1 verbatim).
//   P3 node_final_f: float4 x 4-nodes/thread reduce of 32 partials (r6).
// Fallback to the proven round-5 pipeline if ws_size too small.

#define WSH  14
#define WSZ  16384      // nodes per window (128KB LDS for two fp32 tables)
#define PBF  32         // record slices (multiple of 8 for the XCD swizzle)

// old-path constants (fallback)
#define OWSH 13
#define OWSZ 8192
#define OPB  16
#define OFPS 8192.0f
#define OQBIAS (1 << 20)
#define OQCLMP ((1 << 19) - 1)

// ---------------------------------------------------------------------------
__global__ __launch_bounds__(256) void prep(
    const float* __restrict__ od,
    float* __restrict__ conc,
    unsigned long long* __restrict__ acc,
    int n_nodes)
{
    int n = blockIdx.x * blockDim.x + threadIdx.x;
    if (n >= n_nodes) return;
    conc[n] = od[(long long)n * 48 + 45];   // origin_data[n,15,0]
    if (acc) acc[n] = 0ULL;
}

// ---------------------------------------------------------------------------
// P1: LDS-tiled conv + out2 + bc = val*conc[src].
// val[e] = b + sum_{j<36} flow[e*12+j] * w_re[j],
//   w_re[kh*12+kw*4+i] = conv_w[i*9+kh*3+kw]
__global__ __launch_bounds__(256) void edge_conv(
    const float* __restrict__ flow, const int* __restrict__ ei,
    const float* __restrict__ conv_w, const float* __restrict__ conv_b,
    const float* __restrict__ conc,
    float* __restrict__ out2, float* __restrict__ bcv, int n_edges)
{
    __shared__ float w[40];
    __shared__ __align__(16) float4 stg[774];   // 258 rows x 3 float4 (12.4KB)

    const int t = threadIdx.x;
    if (t < 36) {
        int i  = t & 3;
        int kw = (t >> 2) % 3;
        int kh = t / 12;
        w[t] = conv_w[i * 9 + kh * 3 + kw];
    }
    if (t == 36) w[36] = conv_b[0];

    const long long E0 = (long long)blockIdx.x * 256;
    const long long e  = E0 + t;
    const bool live = (e < n_edges);

    // hoisted index + gather chains (independent of staging)
    int s = 0, d = 0;
    if (live) { s = ei[e]; d = ei[n_edges + e]; }
    float cs = live ? conc[s] : 0.f;            // L2-resident gather (400KB)

    // stage: rows E0..E0+257, consecutive coalesced float4 (each line ONCE)
    const long long rows_avail = (long long)n_edges + 2 - E0;  // flow has NE+2 rows
    const int nf4 = (int)(3 * (rows_avail < 258 ? rows_avail : 258));
    const float4* fb = (const float4*)flow + E0 * 3;
    for (int i = t; i < nf4; i += 256) stg[i] = fb[i];
    __syncthreads();

    if (!live) return;

    // conv from LDS: f4 indices 3t..3t+8 = rows t,t+1,t+2 (stride-3-f4 reads
    // keep all 32 banks busy every cycle -> no throughput conflict)
    const float4* fp = &stg[t * 3];
    float acc = w[36];
#pragma unroll
    for (int q = 0; q < 9; ++q) {
        float4 v = fp[q];
        acc = fmaf(v.x, w[q * 4 + 0], acc);
        acc = fmaf(v.y, w[q * 4 + 1], acc);
        acc = fmaf(v.z, w[q * 4 + 2], acc);
        acc = fmaf(v.w, w[q * 4 + 3], acc);
    }

    float* o = out2 + e * 3;
    o[0] = (float)s;
    o[1] = (float)d;
    o[2] = acc;
    bcv[e] = acc * cs;
}

// ---------------------------------------------------------------------------
// P2: windowed LDS accumulation (round-1 verbatim — proven).
__global__ __launch_bounds__(1024) void accum_f(
    const float* __restrict__ out2,
    const float* __restrict__ bcv,
    float* __restrict__ pA,
    float* __restrict__ pB,
    int n_edges, int n_win, int stride)
{
    __shared__ float tA[WSZ];
    __shared__ float tB[WSZ];

    const int xcd = blockIdx.x & 7;
    const int i   = blockIdx.x >> 3;
    const int j   = i / n_win;                 // 0 .. PBF/8-1
    const int sl  = xcd * (PBF >> 3) + j;      // slice id
    const int w   = i - j * n_win;             // window id

    const int t = threadIdx.x;
    for (int k = t; k < WSZ; k += 1024) { tA[k] = 0.f; tB[k] = 0.f; }
    __syncthreads();

    const long long e0 = (long long)sl * n_edges / PBF;
    const long long e1 = (long long)(sl + 1) * n_edges / PBF;

#define PROC(fs, fd, vv, bb)                                          \
    {                                                                  \
        int s_ = (int)(fs), d_ = (int)(fd);                            \
        if (s_ != d_) {                                                \
            if ((s_ >> WSH) == w) atomicAdd(&tA[s_ & (WSZ - 1)], (vv));\
            if ((d_ >> WSH) == w) atomicAdd(&tB[d_ & (WSZ - 1)], (bb));\
        }                                                              \
    }

    long long e = e0 + t;
    for (; e + 3 * 1024 < e1; e += 4 * 1024) {
        const float* r  = out2 + e * 3;
        const float* bb = bcv + e;
        float fs0 = r[0],    fd0 = r[1],    v0 = r[2];
        float fs1 = r[3072], fd1 = r[3073], v1 = r[3074];
        float fs2 = r[6144], fd2 = r[6145], v2 = r[6146];
        float fs3 = r[9216], fd3 = r[9217], v3 = r[9218];
        float b0 = bb[0], b1 = bb[1024], b2 = bb[2048], b3 = bb[3072];
        PROC(fs0, fd0, v0, b0);
        PROC(fs1, fd1, v1, b1);
        PROC(fs2, fd2, v2, b2);
        PROC(fs3, fd3, v3, b3);
    }
    for (; e < e1; e += 1024) {
        const float* r = out2 + e * 3;
        float fs = r[0], fd = r[1], vv = r[2];
        float bb = bcv[e];
        PROC(fs, fd, vv, bb);
    }
#undef PROC
    __syncthreads();

    float* dA = pA + (long long)sl * stride + ((long long)w << WSH);
    float* dB = pB + (long long)sl * stride + ((long long)w << WSH);
    for (int k = t; k < (WSZ >> 2); k += 1024) {
        ((float4*)dA)[k] = ((const float4*)tA)[k];
        ((float4*)dB)[k] = ((const float4*)tB)[k];
    }
}

// ---------------------------------------------------------------------------
// P3: vectorized reduce of PBF partials (4 nodes/thread, float4) + compose.
__global__ __launch_bounds__(256) void node_final_f(
    const float* __restrict__ od,
    const float* __restrict__ conc,
    const float* __restrict__ pA,
    const float* __restrict__ pB,
    float* __restrict__ out, int n_nodes, int stride)
{
    const int n0 = (blockIdx.x * 256 + threadIdx.x) * 4;
    if (n0 >= n_nodes) return;

    if (n0 + 4 <= n_nodes) {
        float4 a = make_float4(0.f, 0.f, 0.f, 0.f);
        float4 b = make_float4(0.f, 0.f, 0.f, 0.f);
#pragma unroll 8
        for (int sl = 0; sl < PBF; ++sl) {
            float4 va = *(const float4*)(pA + (size_t)sl * stride + n0);
            float4 vb = *(const float4*)(pB + (size_t)sl * stride + n0);
            a.x += va.x; a.y += va.y; a.z += va.z; a.w += va.w;
            b.x += vb.x; b.y += vb.y; b.z += vb.z; b.w += vb.w;
        }
        float4 c4 = *(const float4*)(conc + n0);
        float av[4] = {a.x, a.y, a.z, a.w};
        float bv[4] = {b.x, b.y, b.z, b.w};
        float cv[4] = {c4.x, c4.y, c4.z, c4.w};
        float rv[4];
#pragma unroll
        for (int j = 0; j < 4; ++j) {
            int n = n0 + j;
            long long bi = (long long)n * 48 + 45;
            float p  = od[bi + 1];
            float is = 1.0f / od[bi + 2];
            float r = cv[j];
            if (n != n_nodes - 1)
                r += (bv[j] - av[j] * cv[j]) * is + 0.0052f * p * is;
            rv[j] = r;
        }
        *(float4*)(out + n0) = make_float4(rv[0], rv[1], rv[2], rv[3]);
    } else {
        for (int n = n0; n < n_nodes; ++n) {
            float a = 0.f, b = 0.f;
#pragma unroll 8
            for (int sl = 0; sl < PBF; ++sl) {
                a += pA[(size_t)sl * stride + n];
                b += pB[(size_t)sl * stride + n];
            }
            long long bi = (long long)n * 48 + 45;
            float c  = conc[n];
            float p  = od[bi + 1];
            float is = 1.0f / od[bi + 2];
            float r = c;
            if (n != n_nodes - 1)
                r += (b - a * c) * is + 0.0052f * p * is;
            out[n] = r;
        }
    }
}

// ---------------------------------------------------------------------------
// Fallback path (round-5 proven): flat records + windowed scan + u64 atomics.
__global__ __launch_bounds__(256) void edge_conv_o(
    const float* __restrict__ flow, const int* __restrict__ ei,
    const float* __restrict__ conv_w, const float* __restrict__ conv_b,
    float* __restrict__ out2, int n_edges)
{
    __shared__ float w[40];
    int t = threadIdx.x;
    if (t < 36) {
        int i  = t & 3;
        int kw = (t >> 2) % 3;
        int kh = t / 12;
        w[t] = conv_w[i * 9 + kh * 3 + kw];
    }
    if (t == 36) w[36] = conv_b[0];
    __syncthreads();

    int e = blockIdx.x * blockDim.x + t;
    if (e >= n_edges) return;

    const float4* fp = (const float4*)(flow + (long long)e * 12);
    float acc = w[36];
#pragma unroll
    for (int q = 0; q < 9; ++q) {
        float4 v = fp[q];
        acc = fmaf(v.x, w[q * 4 + 0], acc);
        acc = fmaf(v.y, w[q * 4 + 1], acc);
        acc = fmaf(v.z, w[q * 4 + 2], acc);
        acc = fmaf(v.w, w[q * 4 + 3], acc);
    }

    float* o = out2 + (long long)e * 3;
    o[0] = (float)ei[e];
    o[1] = (float)ei[n_edges + e];
    o[2] = acc;
}

__global__ __launch_bounds__(1024) void accum_o(
    const float* __restrict__ out2,
    const float* __restrict__ conc,
    unsigned long long* __restrict__ acc,
    int n_edges, int n_nodes)
{
    __shared__ float tA[OWSZ];
    __shared__ float tB[OWSZ];

    const int w    = blockIdx.x / OPB;
    const int sl   = blockIdx.x % OPB;
    const int base = w << OWSH;

    for (int i = threadIdx.x; i < OWSZ; i += 1024) { tA[i] = 0.f; tB[i] = 0.f; }
    __syncthreads();

    const long long e0 = (long long)sl * n_edges / OPB;
    const long long e1 = (long long)(sl + 1) * n_edges / OPB;
    for (long long e = e0 + threadIdx.x; e < e1; e += 1024) {
        const float* r = out2 + e * 3;
        float fs = r[0], fd = r[1], v = r[2];
        int s = (int)fs, d = (int)fd;
        if (s == d) continue;
        if ((s >> OWSH) == w) atomicAdd(&tA[s - base], v);
        if ((d >> OWSH) == w) atomicAdd(&tB[d - base], v * conc[s]);
    }
    __syncthreads();

    for (int i = threadIdx.x; i < OWSZ; i += 1024) {
        int n = base + i;
        if (n >= n_nodes) continue;
        float a = tA[i], b = tB[i];
        if (a == 0.f && b == 0.f) continue;
        int qa = __float2int_rn(a * OFPS);
        int qb = __float2int_rn(b * OFPS);
        qa = min(max(qa, -OQCLMP), OQCLMP);
        qb = min(max(qb, -OQCLMP), OQCLMP);
        unsigned long long enc =
            ((unsigned long long)(unsigned)(qa + OQBIAS) << 37) +
            ((unsigned long long)(unsigned)(qb + OQBIAS) << 10) + 1ULL;
        atomicAdd(acc + n, enc);
    }
}

__global__ __launch_bounds__(256) void node_final_o(
    const float* __restrict__ od,
    const float* __restrict__ conc,
    const unsigned long long* __restrict__ acc,
    float* __restrict__ out, int n_nodes)
{
    int n = blockIdx.x * blockDim.x + threadIdx.x;
    if (n >= n_nodes) return;

    unsigned long long t = acc[n];
    long long cnt = (long long)(t & 1023ULL);
    unsigned long long t2 = t >> 10;
    long long sbr = (long long)(t2 & ((1ULL << 27) - 1));
    long long sar = (long long)(t2 >> 27);
    float a = (float)(sar - cnt * OQBIAS) * (1.0f / OFPS);
    float b = (float)(sbr - cnt * OQBIAS) * (1.0f / OFPS);

    long long bi = (long long)n * 48 + 45;
    float c  = conc[n];
    float p  = od[bi + 1];
    float is = 1.0f / od[bi + 2];

    float r = c;
    if (n != n_nodes - 1)
        r += (b - a * c) * is + 0.0052f * p * is;
    out[n] = r;
}

// ---------------------------------------------------------------------------
extern "C" void kernel_launch(void* const* d_in, const int* in_sizes, int n_in,
                              void* d_out, int out_size, void* d_ws, size_t ws_size,
                              hipStream_t stream) {
    const float* od   = (const float*)d_in[0];
    const float* flow = (const float*)d_in[1];
    const float* cw   = (const float*)d_in[2];
    const float* cb   = (const float*)d_in[3];
    const int*   ei   = (const int*)d_in[4];

    const int n_nodes = in_sizes[0] / 48;
    const int n_edges = in_sizes[4] / 2;

    float* out_res = (float*)d_out;        // (NN,)
    float* out2    = out_res + n_nodes;    // (NE,3)

    dim3 blk(256);
    dim3 grid_nodes((n_nodes + 255) / 256);

    // --- full-path workspace layout (round-1) ---------------------------
    const int n_win  = (n_nodes + WSZ - 1) >> WSH;     // 7
    const int stride = n_win << WSH;                   // padded node count
    size_t off = 0;
    size_t o_conc = off; off += (((size_t)n_nodes * 4) + 255) & ~255ULL;
    size_t o_bc   = off; off += (((size_t)n_edges * 4) + 255) & ~255ULL;
    size_t o_pA   = off; off += (((size_t)PBF * stride * 4) + 255) & ~255ULL;
    size_t o_pB   = off; off += (((size_t)PBF * stride * 4) + 255) & ~255ULL;
    const bool full = (ws_size >= off);

    float* conc = (float*)((char*)d_ws + o_conc);

    if (full) {
        float* bcv = (float*)((char*)d_ws + o_bc);
        float* pA  = (float*)((char*)d_ws + o_pA);
        float* pB  = (float*)((char*)d_ws + o_pB);

        dim3 grid_ec((n_edges + 255) / 256);
        dim3 grid_nf(((n_nodes + 3) / 4 + 255) / 256);

        prep<<<grid_nodes, blk, 0, stream>>>(od, conc, nullptr, n_nodes);
        edge_conv<<<grid_ec, blk, 0, stream>>>(flow, ei, cw, cb, conc,
                                               out2, bcv, n_edges);
        accum_f<<<dim3(n_win * PBF), dim3(1024), 0, stream>>>(
            out2, bcv, pA, pB, n_edges, n_win, stride);
        node_final_f<<<grid_nf, blk, 0, stream>>>(od, conc, pA, pB,
                                                  out_res, n_nodes, stride);
    } else {
        // round-5 pipeline
        unsigned long long* acc =
            (unsigned long long*)((char*)d_ws + (((size_t)n_nodes * 4 + 7) / 8 * 8));
        const int n_win_o = (n_nodes + OWSZ - 1) >> OWSH;
        dim3 grid_edges((n_edges + 255) / 256);

        prep<<<grid_nodes, blk, 0, stream>>>(od, conc, acc, n_nodes);
        edge_conv_o<<<grid_edges, blk, 0, stream>>>(flow, ei, cw, cb, out2, n_edges);
        accum_o<<<dim3(n_win_o * OPB), dim3(1024), 0, stream>>>(
            out2, conc, acc, n_edges, n_nodes);
        node_final_o<<<grid_nodes, blk, 0, stream>>>(od, conc, acc,
                                                     out_res, n_nodes);
    }
}